// Round 2
// baseline (267.279 us; speedup 1.0000x reference)
//
#include <hip/hip_runtime.h>
#include <stdint.h>

typedef unsigned short u16;
typedef unsigned int   u32;
typedef short s16x8 __attribute__((ext_vector_type(8)));
typedef float f32x4 __attribute__((ext_vector_type(4)));

#define NB    16384   // batch
#define NIN   1024
#define WLY   512
#define NLAY  8
#define NNODE (NIN + NLAY * WLY)   // 5120

__device__ __forceinline__ u16 f2bf(float f) {
  union { float f; u32 u; } c; c.f = f;
  return (u16)((c.u + 0x7fffu + ((c.u >> 16) & 1u)) >> 16);   // RNE
}
__device__ __forceinline__ float bf2f(u16 h) {
  union { u32 u; float f; } c; c.u = ((u32)h) << 16;
  return c.f;
}

// ---------- prep: Wm_swz[l*512+m][k] = bf16(W*mask)[m][k ^ ((m&7)<<3)] ----------
__global__ void prep_w(const float* __restrict__ W, const float* __restrict__ Mk,
                       u16* __restrict__ Wm) {
  int id  = blockIdx.x * 256 + threadIdx.x;   // 262144 = 4096 rows * 64 chunks
  int row = id >> 6;                          // l*512 + m
  int m   = row & 511;
  int c8  = id & 63;                          // 8-element chunk along k
  size_t base = ((size_t)row << 9) + ((size_t)c8 << 3);
  const float4* w4 = (const float4*)(W + base);
  const float4* k4 = (const float4*)(Mk + base);
  float4 w0 = w4[0], w1 = w4[1];
  float4 k0 = k4[0], k1 = k4[1];
  u32 p0 = (u32)f2bf(w0.x * k0.x) | ((u32)f2bf(w0.y * k0.y) << 16);
  u32 p1 = (u32)f2bf(w0.z * k0.z) | ((u32)f2bf(w0.w * k0.w) << 16);
  u32 p2 = (u32)f2bf(w1.x * k1.x) | ((u32)f2bf(w1.y * k1.y) << 16);
  u32 p3 = (u32)f2bf(w1.z * k1.z) | ((u32)f2bf(w1.w * k1.w) << 16);
  uint4 v; v.x = p0; v.y = p1; v.z = p2; v.w = p3;
  int kd = (c8 << 3) ^ ((m & 7) << 3);        // pre-swizzle (element units)
  *(uint4*)(Wm + ((size_t)row << 9) + kd) = v;
}

// ---------- x (B,1024) f32 -> V[c][b] bf16 for c<1024 ----------
__global__ void transpose_x(const float* __restrict__ x, u16* __restrict__ V) {
  __shared__ __align__(16) float tile[64 * 128];   // [b][c]
  int t  = threadIdx.x;
  int b0 = blockIdx.x * 64;
  int c0 = blockIdx.y * 128;
  #pragma unroll
  for (int it = 0; it < 8; ++it) {
    int id = t + it * 256;
    int b = id >> 5, c4 = id & 31;
    float4 v = *(const float4*)(x + (size_t)(b0 + b) * 1024 + c0 + (c4 << 2));
    *(float4*)(tile + b * 128 + (c4 << 2)) = v;
  }
  __syncthreads();
  int c = t & 63, ch = t >> 6;
  #pragma unroll
  for (int a = 0; a < 2; ++a)
    #pragma unroll
    for (int bb = 0; bb < 2; ++bb) {
      int cc = c + a * 64, chh = ch + bb * 4;   // cc: 0..127, chh: 0..7 (8 b per chunk)
      u32 p[4];
      #pragma unroll
      for (int q = 0; q < 4; ++q) {
        float lo = tile[(chh * 8 + q * 2) * 128 + cc];
        float hi = tile[(chh * 8 + q * 2 + 1) * 128 + cc];
        p[q] = (u32)f2bf(lo) | ((u32)f2bf(hi) << 16);
      }
      uint4 v; v.x = p[0]; v.y = p[1]; v.z = p[2]; v.w = p[3];
      *(uint4*)(V + (size_t)(c0 + cc) * NB + b0 + chh * 8) = v;
    }
}

// ---------- per layer: Gt_swz[n][k] = V[idx[k]][n], pre-swizzled along k ----------
__global__ void gather_t(const u16* __restrict__ V, const int* __restrict__ idx,
                         u16* __restrict__ Gt) {
  __shared__ __align__(16) u16 tile[64 * 128];   // [k][n]
  int t  = threadIdx.x;
  int kb = blockIdx.x * 64;     // 0..7
  int n0 = blockIdx.y * 128;    // 0..127
  #pragma unroll
  for (int i = 0; i < 4; ++i) {
    int kl = (t >> 4) + i * 16;
    int c16 = t & 15;
    int row = idx[kb + kl];
    uint4 v = *(const uint4*)(V + (size_t)row * NB + n0 + (c16 << 3));
    *(uint4*)(tile + kl * 128 + (c16 << 3)) = v;
  }
  __syncthreads();
  int n = t & 63, ch = t >> 6;
  #pragma unroll
  for (int a = 0; a < 2; ++a)
    #pragma unroll
    for (int bb = 0; bb < 2; ++bb) {
      int nn = n + a * 64;          // 0..127
      int c  = ch + bb * 4;         // 0..7 (8 k per chunk)
      u32 p[4];
      #pragma unroll
      for (int q = 0; q < 4; ++q) {
        u16 lo = tile[(c * 8 + q * 2) * 128 + nn];
        u16 hi = tile[(c * 8 + q * 2 + 1) * 128 + nn];
        p[q] = (u32)lo | ((u32)hi << 16);
      }
      uint4 v; v.x = p[0]; v.y = p[1]; v.z = p[2]; v.w = p[3];
      char* dst = (char*)Gt + (size_t)(n0 + nn) * 1024 + kb * 2
                + ((c * 16) ^ ((nn & 7) << 4));
      *(uint4*)dst = v;
    }
}

// ---------- GEMM: V[out0+m][n] = bf16(relu(sum_k Wm[m][k]*Gt[n][k] + bias[m])) ----------
__global__ __launch_bounds__(256, 2) void gemm_relu(
    const u16* __restrict__ Wm,    // layer's 512x512, pre-swizzled
    const u16* __restrict__ Gt,    // 16384x512, pre-swizzled
    const float* __restrict__ bias,
    u16* __restrict__ Vout) {      // row stride NB
  __shared__ __align__(16) u16 Alds[128 * 64];
  __shared__ __align__(16) u16 Blds[128 * 64];
  __shared__ float bias_s[128];
  int t = threadIdx.x;
  int lane = t & 63, w = t >> 6;
  int m0 = blockIdx.x << 7;
  int n0 = blockIdx.y << 7;
  if (t < 128) bias_s[t] = bias[m0 + t];
  int rloc = lane >> 3;            // 0..7 row within 8-row group
  int kbl  = (lane & 7) << 4;      // 0..112 byte within 128B row
  int mlane = lane & 15, g = lane >> 4;
  int wm = (w >> 1) << 6, wn = (w & 1) << 6;

  f32x4 acc[4][4];
  #pragma unroll
  for (int i = 0; i < 4; ++i)
    #pragma unroll
    for (int j = 0; j < 4; ++j)
      acc[i][j] = (f32x4){0.f, 0.f, 0.f, 0.f};

  for (int kt = 0; kt < 8; ++kt) {
    #pragma unroll
    for (int i = 0; i < 4; ++i) {
      int rr = ((w << 2) + i) << 3;   // 8-row group base
      const char* asrc = (const char*)Wm + (size_t)(m0 + rr + rloc) * 1024 + (kt << 7) + kbl;
      const char* bsrc = (const char*)Gt + (size_t)(n0 + rr + rloc) * 1024 + (kt << 7) + kbl;
      __builtin_amdgcn_global_load_lds(
          (const __attribute__((address_space(1))) u32*)asrc,
          (__attribute__((address_space(3))) u32*)(Alds + rr * 64), 16, 0, 0);
      __builtin_amdgcn_global_load_lds(
          (const __attribute__((address_space(1))) u32*)bsrc,
          (__attribute__((address_space(3))) u32*)(Blds + rr * 64), 16, 0, 0);
    }
    __syncthreads();
    #pragma unroll
    for (int ks = 0; ks < 2; ++ks) {
      int kb = (ks << 6) + (g << 4);
      s16x8 af[4], bfr[4];
      #pragma unroll
      for (int mf = 0; mf < 4; ++mf) {
        int m = wm + (mf << 4) + mlane;
        af[mf] = *(const s16x8*)((const char*)Alds + m * 128 + (kb ^ ((m & 7) << 4)));
      }
      #pragma unroll
      for (int nf = 0; nf < 4; ++nf) {
        int n = wn + (nf << 4) + mlane;
        bfr[nf] = *(const s16x8*)((const char*)Blds + n * 128 + (kb ^ ((n & 7) << 4)));
      }
      #pragma unroll
      for (int mf = 0; mf < 4; ++mf)
        #pragma unroll
        for (int nf = 0; nf < 4; ++nf)
          acc[mf][nf] = __builtin_amdgcn_mfma_f32_16x16x32_bf16(
              af[mf], bfr[nf], acc[mf][nf], 0, 0, 0);
    }
    __syncthreads();
  }
  // epilogue: bias + relu + bf16 store
  #pragma unroll
  for (int mf = 0; mf < 4; ++mf)
    #pragma unroll
    for (int nf = 0; nf < 4; ++nf)
      #pragma unroll
      for (int r = 0; r < 4; ++r) {
        int ml = wm + (mf << 4) + (g << 2) + r;
        int nl = wn + (nf << 4) + mlane;
        float v = fmaxf(acc[mf][nf][r] + bias_s[ml], 0.f);
        Vout[(size_t)(m0 + ml) * NB + n0 + nl] = f2bf(v);
      }
}

// ---------- out[b][j] = f32(V[4608+j][b]) ----------
__global__ void final_out(const u16* __restrict__ V, float* __restrict__ out) {
  int t  = threadIdx.x;
  int j0 = blockIdx.x << 6;     // 8 blocks
  int b0 = blockIdx.y << 9;     // 32 blocks
  int j = t & 63, bg = t >> 6;
  const u16* Vb = V + (size_t)(NIN + (NLAY - 1) * WLY + j0 + j) * NB;
  #pragma unroll 4
  for (int p = 0; p < 16; ++p) {
    int b = b0 + ((bg + (p << 2)) << 3);
    uint4 v = *(const uint4*)(Vb + b);
    u32 ww[4] = {v.x, v.y, v.z, v.w};
    #pragma unroll
    for (int q = 0; q < 4; ++q) {
      out[(size_t)(b + 2 * q) * 512 + j0 + j]     = bf2f((u16)(ww[q] & 0xffffu));
      out[(size_t)(b + 2 * q + 1) * 512 + j0 + j] = bf2f((u16)(ww[q] >> 16));
    }
  }
}

extern "C" void kernel_launch(void* const* d_in, const int* in_sizes, int n_in,
                              void* d_out, int out_size, void* d_ws, size_t ws_size,
                              hipStream_t stream) {
  (void)in_sizes; (void)n_in; (void)out_size; (void)ws_size;
  const float* x    = (const float*)d_in[0];
  const float* W    = (const float*)d_in[1];
  const float* Mk   = (const float*)d_in[2];
  const float* bias = (const float*)d_in[3];
  const int*  inidx = (const int*)d_in[4];
  float* out = (float*)d_out;

  char* ws = (char*)d_ws;
  u16* V  = (u16*)ws;                                        // 5120*16384*2 = 160 MiB
  u16* Wm = (u16*)(ws + (size_t)NNODE * NB * 2);             // 8*512*512*2 = 4 MiB
  u16* Gt = (u16*)(ws + (size_t)NNODE * NB * 2 + (size_t)NLAY * WLY * WLY * 2); // 16 MiB

  prep_w<<<dim3(1024), 256, 0, stream>>>(W, Mk, Wm);
  transpose_x<<<dim3(256, 8), 256, 0, stream>>>(x, V);
  for (int l = 0; l < NLAY; ++l) {
    gather_t<<<dim3(8, 128), 256, 0, stream>>>(V, inidx + l * WLY, Gt);
    gemm_relu<<<dim3(4, 128), 256, 0, stream>>>(
        Wm + (size_t)l * WLY * WLY, Gt, bias + l * WLY,
        V + (size_t)(NIN + l * WLY) * NB);
  }
  final_out<<<dim3(8, 32), 256, 0, stream>>>(V, out);
}

// Round 3
// 124.651 us; speedup vs baseline: 2.1442x; 2.1442x over previous
//
#include <hip/hip_runtime.h>
#include <stdint.h>

typedef unsigned short u16;
typedef unsigned int   u32;
typedef short s16x8 __attribute__((ext_vector_type(8)));
typedef float f32x4 __attribute__((ext_vector_type(4)));

#define NB    16384   // batch
#define NIN   1024
#define WLY   512
#define NLAY  8
#define NNODE (NIN + NLAY * WLY)   // 5120
#define BN    64      // batch columns per block

__device__ __forceinline__ u16 f2bf(float f) {
  union { float f; u32 u; } c; c.f = f;
  return (u16)((c.u + 0x7fffu + ((c.u >> 16) & 1u)) >> 16);   // RNE
}

// ---------- prep: fragment-major Wfrag ----------
// chunk = ((l*8 + kt)*32 + mb)*2 + kf ; within chunk: lane*8 elems
// lane maps: m = mb*16 + (lane&15), k = kt*64 + kf*32 + (lane>>4)*8 + j
__global__ void prep_w(const float* __restrict__ W, const float* __restrict__ Mk,
                       u16* __restrict__ Wm) {
  int id   = blockIdx.x * 256 + threadIdx.x;   // 262144
  int lane = id & 63;
  int chunk = id >> 6;                         // 0..4095
  int kf = chunk & 1;
  int mb = (chunk >> 1) & 31;
  int kt = (chunk >> 6) & 7;
  int l  = chunk >> 9;
  int m  = (mb << 4) + (lane & 15);
  int k0 = (kt << 6) + (kf << 5) + ((lane >> 4) << 3);
  size_t base = ((size_t)l << 18) + (size_t)m * 512 + k0;
  const float4* w4 = (const float4*)(W + base);
  const float4* k4 = (const float4*)(Mk + base);
  float4 w0 = w4[0], w1 = w4[1];
  float4 k0v = k4[0], k1v = k4[1];
  u32 p0 = (u32)f2bf(w0.x * k0v.x) | ((u32)f2bf(w0.y * k0v.y) << 16);
  u32 p1 = (u32)f2bf(w0.z * k0v.z) | ((u32)f2bf(w0.w * k0v.w) << 16);
  u32 p2 = (u32)f2bf(w1.x * k1v.x) | ((u32)f2bf(w1.y * k1v.y) << 16);
  u32 p3 = (u32)f2bf(w1.z * k1v.z) | ((u32)f2bf(w1.w * k1v.w) << 16);
  uint4 v; v.x = p0; v.y = p1; v.z = p2; v.w = p3;
  *(uint4*)(Wm + ((size_t)chunk << 9) + (lane << 3)) = v;
}

// ---------- fused 8-layer network, one block per 64-batch slice ----------
__global__ __launch_bounds__(512, 2) void fused_net(
    const float* __restrict__ x, const u16* __restrict__ Wfrag,
    const float* __restrict__ bias, const int* __restrict__ in_idx,
    u16* __restrict__ V, float* __restrict__ out) {

  __shared__ __align__(16) u16 Graw[2][4096];   // [64 k][64 n]
  __shared__ __align__(16) u16 Gswz[2][4096];   // [64 n][128B swz k]
  __shared__ int   idx_s[512];
  __shared__ float bias_s[512];
  __shared__ __align__(16) u16 Ebuf[512 * 72];  // [m][n] stride 72

  int t = threadIdx.x;
  int lane = t & 63, w = t >> 6;
  int mlane = lane & 15, g = lane >> 4;
  int n0 = blockIdx.x * BN;

  // ---- x prologue: V[c][n0..n0+64) = bf16(x[n][c]) for c<1024 ----
  float* xt = (float*)Ebuf;                     // [64 b][128 c] = 32KB
  for (int cc = 0; cc < 8; ++cc) {
    #pragma unroll
    for (int it = 0; it < 4; ++it) {
      int cl = t + it * 512;                    // 0..2047
      int b = cl >> 5, p = cl & 31;
      *(float4*)(xt + b * 128 + (p << 2)) =
          *(const float4*)(x + (size_t)(n0 + b) * 1024 + cc * 128 + (p << 2));
    }
    __syncthreads();
    {
      int c = t >> 2, seg = t & 3;              // c 0..127, seg 0..3
      u32 p[8];
      #pragma unroll
      for (int i = 0; i < 8; ++i) {
        u16 lo = f2bf(xt[(seg * 16 + 2 * i) * 128 + c]);
        u16 hi = f2bf(xt[(seg * 16 + 2 * i + 1) * 128 + c]);
        p[i] = (u32)lo | ((u32)hi << 16);
      }
      u16* dst = V + (size_t)(cc * 128 + c) * NB + n0 + seg * 16;
      uint4 v0; v0.x = p[0]; v0.y = p[1]; v0.z = p[2]; v0.w = p[3];
      uint4 v1; v1.x = p[4]; v1.y = p[5]; v1.z = p[6]; v1.w = p[7];
      *(uint4*)dst = v0;
      *(uint4*)(dst + 8) = v1;
    }
    __syncthreads();
  }

#define STAGE(KT, BUF) do {                                                    \
    int k_ = (w << 3) + (lane >> 3);                                           \
    int row_ = idx_s[((KT) << 6) + k_];                                        \
    const u16* src_ = V + (size_t)row_ * NB + n0 + ((lane & 7) << 3);          \
    __builtin_amdgcn_global_load_lds(                                          \
        (const __attribute__((address_space(1))) u32*)src_,                    \
        (__attribute__((address_space(3))) u32*)(&Graw[BUF][w << 9]), 16, 0, 0); \
  } while (0)

  // ---- layer loop ----
  for (int l = 0; l < NLAY; ++l) {
    idx_s[t]  = in_idx[(l << 9) + t];
    bias_s[t] = bias[(l << 9) + t];
    __syncthreads();

    const u16* Wl = Wfrag + ((size_t)l << 18);
    int node_out = NIN + l * WLY;

    f32x4 acc[4][4];
    #pragma unroll
    for (int i = 0; i < 4; ++i)
      #pragma unroll
      for (int j = 0; j < 4; ++j)
        acc[i][j] = (f32x4){0.f, 0.f, 0.f, 0.f};

    STAGE(0, 0);
    __syncthreads();

    #pragma unroll
    for (int kt = 0; kt < 8; ++kt) {
      const int cur = kt & 1;
      // A fragments: direct global->VGPR, contiguous 1KB per wave-instr
      s16x8 a[4][2];
      #pragma unroll
      for (int mb = 0; mb < 4; ++mb)
        #pragma unroll
        for (int kf = 0; kf < 2; ++kf)
          a[mb][kf] = *(const s16x8*)(Wl +
              ((size_t)(((kt * 32 + (w << 2) + mb) << 1) + kf) << 9) + (lane << 3));
      // transpose Graw[cur] -> Gswz[cur]  (k-major -> n-major swizzled)
      {
        int n = t & 63, kc = t >> 6;
        u32 p[4];
        #pragma unroll
        for (int i = 0; i < 4; ++i) {
          u16 lo = Graw[cur][(kc * 8 + 2 * i) * 64 + n];
          u16 hi = Graw[cur][(kc * 8 + 2 * i + 1) * 64 + n];
          p[i] = (u32)lo | ((u32)hi << 16);
        }
        uint4 vv; vv.x = p[0]; vv.y = p[1]; vv.z = p[2]; vv.w = p[3];
        *(uint4*)((char*)Gswz[cur] + n * 128 + ((kc * 16) ^ ((n & 7) << 4))) = vv;
      }
      if (kt < 7) { STAGE(kt + 1, cur ^ 1); }
      __syncthreads();
      // MFMA
      #pragma unroll
      for (int kf = 0; kf < 2; ++kf) {
        s16x8 bfr[4];
        #pragma unroll
        for (int nf = 0; nf < 4; ++nf) {
          int n = (nf << 4) + mlane;
          bfr[nf] = *(const s16x8*)((const char*)Gswz[cur] + n * 128 +
                                    (((kf << 6) + (g << 4)) ^ ((n & 7) << 4)));
        }
        #pragma unroll
        for (int mb = 0; mb < 4; ++mb)
          #pragma unroll
          for (int nf = 0; nf < 4; ++nf)
            acc[mb][nf] = __builtin_amdgcn_mfma_f32_16x16x32_bf16(
                a[mb][kf], bfr[nf], acc[mb][nf], 0, 0, 0);
      }
    }

    if (l < NLAY - 1) {
      // epilogue: bias+relu -> bf16 Ebuf[m][n], then coalesced V write
      #pragma unroll
      for (int mb = 0; mb < 4; ++mb)
        #pragma unroll
        for (int nf = 0; nf < 4; ++nf)
          #pragma unroll
          for (int r = 0; r < 4; ++r) {
            int m = (w << 6) + (mb << 4) + (g << 2) + r;
            int n = (nf << 4) + mlane;
            Ebuf[m * 72 + n] = f2bf(fmaxf(acc[mb][nf][r] + bias_s[m], 0.f));
          }
      __syncthreads();
      #pragma unroll
      for (int it = 0; it < 8; ++it) {
        int row = (it << 6) + (t >> 3), part = t & 7;
        *(uint4*)(V + (size_t)(node_out + row) * NB + n0 + (part << 3)) =
            *(uint4*)(&Ebuf[row * 72 + (part << 3)]);
      }
      __syncthreads();   // V writes drained before next layer's gather
    } else {
      // final layer: bias+relu -> f32 out[b][j] directly (j = m, b = n0+n)
      #pragma unroll
      for (int mb = 0; mb < 4; ++mb)
        #pragma unroll
        for (int nf = 0; nf < 4; ++nf) {
          int n = (nf << 4) + mlane;
          int m0f = (w << 6) + (mb << 4) + (g << 2);
          float4 v;
          v.x = fmaxf(acc[mb][nf][0] + bias_s[m0f + 0], 0.f);
          v.y = fmaxf(acc[mb][nf][1] + bias_s[m0f + 1], 0.f);
          v.z = fmaxf(acc[mb][nf][2] + bias_s[m0f + 2], 0.f);
          v.w = fmaxf(acc[mb][nf][3] + bias_s[m0f + 3], 0.f);
          *(float4*)(out + (size_t)(n0 + n) * 512 + m0f) = v;
        }
    }
  }
#undef STAGE
}

extern "C" void kernel_launch(void* const* d_in, const int* in_sizes, int n_in,
                              void* d_out, int out_size, void* d_ws, size_t ws_size,
                              hipStream_t stream) {
  (void)in_sizes; (void)n_in; (void)out_size; (void)ws_size;
  const float* x    = (const float*)d_in[0];
  const float* W    = (const float*)d_in[1];
  const float* Mk   = (const float*)d_in[2];
  const float* bias = (const float*)d_in[3];
  const int*  inidx = (const int*)d_in[4];
  float* out = (float*)d_out;

  char* ws = (char*)d_ws;
  u16* V     = (u16*)ws;                                   // 160 MiB
  u16* Wfrag = (u16*)(ws + (size_t)NNODE * NB * 2);        // 4 MiB @ 160 MiB

  prep_w<<<dim3(1024), 256, 0, stream>>>(W, Mk, Wfrag);
  fused_net<<<dim3(256), 512, 0, stream>>>(x, Wfrag, bias, inidx, V, out);
}

// Round 4
// 123.202 us; speedup vs baseline: 2.1694x; 1.0118x over previous
//
#include <hip/hip_runtime.h>
#include <stdint.h>

typedef unsigned short u16;
typedef unsigned int   u32;
typedef short s16x8 __attribute__((ext_vector_type(8)));
typedef float f32x4 __attribute__((ext_vector_type(4)));

#define NB    16384   // batch
#define NIN   1024
#define WLY   512
#define NLAY  8
#define NNODE (NIN + NLAY * WLY)   // 5120
#define BN    64      // batch columns per block

__device__ __forceinline__ u16 f2bf(float f) {
  union { float f; u32 u; } c; c.f = f;
  return (u16)((c.u + 0x7fffu + ((c.u >> 16) & 1u)) >> 16);   // RNE
}
__device__ __forceinline__ float bf2f(u16 h) {
  union { u32 u; float f; } c; c.u = ((u32)h) << 16;
  return c.f;
}

#define SCHED0() __builtin_amdgcn_sched_barrier(0)
#define BAR()    __builtin_amdgcn_s_barrier()
#define WAITVM_IMPL(N) asm volatile("s_waitcnt vmcnt(" #N ")" ::: "memory")
#define WAITVM(N) WAITVM_IMPL(N)
#define WAITLG()  asm volatile("s_waitcnt lgkmcnt(0)" ::: "memory")

// ---------- prep: fragment-major Wfrag (r3-proven) ----------
// chunk = ((l*8 + kt)*32 + mb)*2 + kf ; lane maps: m = mb*16 + (lane&15),
// k = kt*64 + kf*32 + (lane>>4)*8 + j
__global__ void prep_w(const float* __restrict__ W, const float* __restrict__ Mk,
                       u16* __restrict__ Wm) {
  int id   = blockIdx.x * 256 + threadIdx.x;   // 262144
  int lane = id & 63;
  int chunk = id >> 6;                         // 0..4095
  int kf = chunk & 1;
  int mb = (chunk >> 1) & 31;
  int kt = (chunk >> 6) & 7;
  int l  = chunk >> 9;
  int m  = (mb << 4) + (lane & 15);
  int k0 = (kt << 6) + (kf << 5) + ((lane >> 4) << 3);
  size_t base = ((size_t)l << 18) + (size_t)m * 512 + k0;
  const float4* w4 = (const float4*)(W + base);
  const float4* k4 = (const float4*)(Mk + base);
  float4 w0 = w4[0], w1 = w4[1];
  float4 k0v = k4[0], k1v = k4[1];
  u32 p0 = (u32)f2bf(w0.x * k0v.x) | ((u32)f2bf(w0.y * k0v.y) << 16);
  u32 p1 = (u32)f2bf(w0.z * k0v.z) | ((u32)f2bf(w0.w * k0v.w) << 16);
  u32 p2 = (u32)f2bf(w1.x * k1v.x) | ((u32)f2bf(w1.y * k1v.y) << 16);
  u32 p3 = (u32)f2bf(w1.z * k1v.z) | ((u32)f2bf(w1.w * k1v.w) << 16);
  uint4 v; v.x = p0; v.y = p1; v.z = p2; v.w = p3;
  *(uint4*)(Wm + ((size_t)chunk << 9) + (lane << 3)) = v;
}

// ---------- fused 8-layer network, one block per 64-batch slice ----------
__global__ __launch_bounds__(512, 2) void fused_net(
    const float* __restrict__ x, const u16* __restrict__ Wfrag,
    const float* __restrict__ bias, const int* __restrict__ in_idx,
    u16* __restrict__ V, float* __restrict__ out) {

  __shared__ __align__(16) u16 Graw[4][4096];   // ring of [64 k][64 n] tiles
  __shared__ __align__(16) u16 Gswz[2][4096];   // [64 n][128B swz k] dbuf
  __shared__ __align__(16) u16 Ebuf[512 * 72];  // per-wave epilogue / xt
  __shared__ int   idx_s[512];
  __shared__ float bias_s[512];

  int t = threadIdx.x;
  int lane = t & 63, w = t >> 6;
  int mlane = lane & 15, g = lane >> 4;
  int n0 = blockIdx.x * BN;

  // ---- x prologue: V[c][n0..n0+64) = bf16(x[n][c]) for c<1024 ----
  float* xt = (float*)Ebuf;                     // [64 b][128 c] = 32KB
  for (int cc = 0; cc < 8; ++cc) {
    #pragma unroll
    for (int it = 0; it < 4; ++it) {
      int cl = t + it * 512;                    // 0..2047
      int b = cl >> 5, p = cl & 31;
      *(float4*)(xt + b * 128 + (p << 2)) =
          *(const float4*)(x + (size_t)(n0 + b) * 1024 + cc * 128 + (p << 2));
    }
    __syncthreads();
    {
      int c = t >> 2, seg = t & 3;              // c 0..127, seg 0..3
      u32 p[8];
      #pragma unroll
      for (int i = 0; i < 8; ++i) {
        u16 lo = f2bf(xt[(seg * 16 + 2 * i) * 128 + c]);
        u16 hi = f2bf(xt[(seg * 16 + 2 * i + 1) * 128 + c]);
        p[i] = (u32)lo | ((u32)hi << 16);
      }
      u16* dst = V + (size_t)(cc * 128 + c) * NB + n0 + seg * 16;
      uint4 v0; v0.x = p[0]; v0.y = p[1]; v0.z = p[2]; v0.w = p[3];
      uint4 v1; v1.x = p[4]; v1.y = p[5]; v1.z = p[6]; v1.w = p[7];
      *(uint4*)dst = v0;
      *(uint4*)(dst + 8) = v1;
    }
    __syncthreads();
  }

#define STAGE(KT, R) do {                                                      \
    int k_ = (w << 3) + (lane >> 3);                                           \
    int row_ = idx_s[((KT) << 6) + k_];                                        \
    const u16* src_ = V + (size_t)row_ * NB + n0 + ((lane & 7) << 3);          \
    __builtin_amdgcn_global_load_lds(                                          \
        (const __attribute__((address_space(1))) u32*)src_,                    \
        (__attribute__((address_space(3))) u32*)(&Graw[R][w << 9]), 16, 0, 0); \
  } while (0)

#define LDA(KTN) do {                                                          \
    _Pragma("unroll") for (int mb = 0; mb < 4; ++mb)                           \
    _Pragma("unroll") for (int kf = 0; kf < 2; ++kf)                           \
      a[(KTN) & 1][mb][kf] = *(const s16x8*)(Wl +                              \
          ((size_t)((((KTN) * 32 + (w << 2) + mb) << 1) + kf) << 9) +          \
          (lane << 3));                                                        \
  } while (0)

#define TRANSP(KT) do {                                                        \
    int n_ = t & 63, kc_ = t >> 6;                                             \
    const u16* gb_ = Graw[(KT) & 3];                                           \
    u32 p0_ = (u32)gb_[(kc_ * 8 + 0) * 64 + n_] |                              \
              ((u32)gb_[(kc_ * 8 + 1) * 64 + n_] << 16);                       \
    u32 p1_ = (u32)gb_[(kc_ * 8 + 2) * 64 + n_] |                              \
              ((u32)gb_[(kc_ * 8 + 3) * 64 + n_] << 16);                       \
    u32 p2_ = (u32)gb_[(kc_ * 8 + 4) * 64 + n_] |                              \
              ((u32)gb_[(kc_ * 8 + 5) * 64 + n_] << 16);                       \
    u32 p3_ = (u32)gb_[(kc_ * 8 + 6) * 64 + n_] |                              \
              ((u32)gb_[(kc_ * 8 + 7) * 64 + n_] << 16);                       \
    uint4 vv_; vv_.x = p0_; vv_.y = p1_; vv_.z = p2_; vv_.w = p3_;             \
    *(uint4*)((char*)Gswz[(KT) & 1] + n_ * 128 +                               \
              ((kc_ * 16) ^ ((n_ & 7) << 4))) = vv_;                           \
  } while (0)

#define MM(KT) do {                                                            \
    const char* gs_ = (const char*)Gswz[(KT) & 1];                             \
    _Pragma("unroll") for (int kf = 0; kf < 2; ++kf) {                         \
      s16x8 bfr[4];                                                            \
      _Pragma("unroll") for (int nf = 0; nf < 4; ++nf) {                       \
        int n_ = (nf << 4) + mlane;                                            \
        bfr[nf] = *(const s16x8*)(gs_ + n_ * 128 +                             \
                  (((kf << 6) + (g << 4)) ^ ((n_ & 7) << 4)));                 \
      }                                                                        \
      _Pragma("unroll") for (int mb = 0; mb < 4; ++mb)                         \
      _Pragma("unroll") for (int nf = 0; nf < 4; ++nf)                         \
        acc[mb][nf] = __builtin_amdgcn_mfma_f32_16x16x32_bf16(                 \
            a[(KT) & 1][mb][kf], bfr[nf], acc[mb][nf], 0, 0, 0);               \
    }                                                                          \
  } while (0)

#define BODY(KT, VMN, PRE, POST) do {                                          \
    if (PRE) { LDA((KT) + 1); }                                                \
    SCHED0(); WAITVM(VMN); SCHED0();                                           \
    BAR();                                                                     \
    if (POST) { STAGE((KT) + 3, ((KT) + 3) & 3); }                             \
    TRANSP(KT);                                                                \
    SCHED0(); WAITLG(); BAR(); SCHED0();                                       \
    MM(KT);                                                                    \
  } while (0)

  // ---- layer loop ----
  for (int l = 0; l < NLAY; ++l) {
    idx_s[t]  = in_idx[(l << 9) + t];
    bias_s[t] = bias[(l << 9) + t];
    __syncthreads();   // publishes idx/bias, drains prev epilogue stores

    const u16* Wl = Wfrag + ((size_t)l << 18);
    int node_out = NIN + l * WLY;

    f32x4 acc[4][4];
    #pragma unroll
    for (int i = 0; i < 4; ++i)
      #pragma unroll
      for (int j = 0; j < 4; ++j)
        acc[i][j] = (f32x4){0.f, 0.f, 0.f, 0.f};

    s16x8 a[2][4][2];

    // pipeline prologue: S0,S1,S2 then A0  (queue baseline = 0)
    STAGE(0, 0); STAGE(1, 1); STAGE(2, 2);
    SCHED0();
    LDA(0);
    SCHED0();

    BODY(0, 8, 1, 1);
    BODY(1, 9, 1, 1);
    BODY(2, 9, 1, 1);
    BODY(3, 9, 1, 1);
    BODY(4, 9, 1, 1);
    BODY(5, 9, 1, 0);
    BODY(6, 8, 1, 0);
    BODY(7, 0, 0, 0);

    if (l < NLAY - 1) {
      // wave-private epilogue: bias+relu -> Ebuf[m][72] -> coalesced V write
      #pragma unroll
      for (int mb = 0; mb < 4; ++mb)
        #pragma unroll
        for (int nf = 0; nf < 4; ++nf)
          #pragma unroll
          for (int r = 0; r < 4; ++r) {
            int m = (w << 6) + (mb << 4) + (g << 2) + r;
            int n = (nf << 4) + mlane;
            Ebuf[m * 72 + n] = f2bf(fmaxf(acc[mb][nf][r] + bias_s[m], 0.f));
          }
      #pragma unroll
      for (int it = 0; it < 8; ++it) {
        int row = (w << 6) + (it << 3) + (lane >> 3);
        uint4 vv = *(uint4*)(Ebuf + row * 72 + ((lane & 7) << 3));
        *(uint4*)(V + (size_t)(node_out + row) * NB + n0 + ((lane & 7) << 3)) = vv;
      }
      // no barrier: Ebuf rows + V rows are wave-private; next-layer
      // __syncthreads drains the stores before gathers read them.
    } else {
      // final layer: stride-66 Ebuf (bank-clean column reads) -> f32 out
      #pragma unroll
      for (int mb = 0; mb < 4; ++mb)
        #pragma unroll
        for (int nf = 0; nf < 4; ++nf)
          #pragma unroll
          for (int r = 0; r < 4; ++r) {
            int m = (w << 6) + (mb << 4) + (g << 2) + r;
            int n = (nf << 4) + mlane;
            Ebuf[m * 66 + n] = f2bf(fmaxf(acc[mb][nf][r] + bias_s[m], 0.f));
          }
      __syncthreads();
      #pragma unroll
      for (int pn = 0; pn < 8; ++pn)
        #pragma unroll
        for (int h = 0; h < 2; ++h) {
          int n = (t >> 6) + (pn << 3);
          int mbase = ((t & 63) << 2) + (h << 8);
          float4 v;
          v.x = bf2f(Ebuf[(mbase + 0) * 66 + n]);
          v.y = bf2f(Ebuf[(mbase + 1) * 66 + n]);
          v.z = bf2f(Ebuf[(mbase + 2) * 66 + n]);
          v.w = bf2f(Ebuf[(mbase + 3) * 66 + n]);
          *(float4*)(out + (size_t)(n0 + n) * 512 + mbase) = v;
        }
    }
  }
#undef STAGE
#undef LDA
#undef TRANSP
#undef MM
#undef BODY
}

extern "C" void kernel_launch(void* const* d_in, const int* in_sizes, int n_in,
                              void* d_out, int out_size, void* d_ws, size_t ws_size,
                              hipStream_t stream) {
  (void)in_sizes; (void)n_in; (void)out_size; (void)ws_size;
  const float* x    = (const float*)d_in[0];
  const float* W    = (const float*)d_in[1];
  const float* Mk   = (const float*)d_in[2];
  const float* bias = (const float*)d_in[3];
  const int*  inidx = (const int*)d_in[4];
  float* out = (float*)d_out;

  char* ws = (char*)d_ws;
  u16* V     = (u16*)ws;                                   // 160 MiB
  u16* Wfrag = (u16*)(ws + (size_t)NNODE * NB * 2);        // 4 MiB @ 160 MiB

  prep_w<<<dim3(1024), 256, 0, stream>>>(W, Mk, Wfrag);
  fused_net<<<dim3(256), 512, 0, stream>>>(x, Wfrag, bias, inidx, V, out);
}